// Round 1
// baseline (1099.208 us; speedup 1.0000x reference)
//
#include <hip/hip_runtime.h>
#include <math.h>

#define N_NODES 50000
#define M_NB 16
#define K_CAPS 8
#define DD 16
#define D_DIM 128
#define ROUTIT 6

// ---------------------------------------------------------------------------
// K1: per-capsule L2 normalize: xn[n,k,:] = x[n,k,:] / max(||x[n,k,:]||, 1e-12)
// one thread per capsule (16 contiguous floats)
// ---------------------------------------------------------------------------
__global__ void normalize_kernel(const float* __restrict__ x,
                                 float* __restrict__ xn) {
    int tid = blockIdx.x * blockDim.x + threadIdx.x;
    if (tid >= N_NODES * K_CAPS) return;
    const float4* p = reinterpret_cast<const float4*>(x + (size_t)tid * DD);
    float4 a0 = p[0], a1 = p[1], a2 = p[2], a3 = p[3];
    float s = a0.x*a0.x + a0.y*a0.y + a0.z*a0.z + a0.w*a0.w
            + a1.x*a1.x + a1.y*a1.y + a1.z*a1.z + a1.w*a1.w
            + a2.x*a2.x + a2.y*a2.y + a2.z*a2.z + a2.w*a2.w
            + a3.x*a3.x + a3.y*a3.y + a3.z*a3.z + a3.w*a3.w;
    float inv = 1.0f / fmaxf(sqrtf(s), 1e-12f);
    float4* q = reinterpret_cast<float4*>(xn + (size_t)tid * DD);
    a0.x *= inv; a0.y *= inv; a0.z *= inv; a0.w *= inv;
    a1.x *= inv; a1.y *= inv; a1.z *= inv; a1.w *= inv;
    a2.x *= inv; a2.y *= inv; a2.z *= inv; a2.w *= inv;
    a3.x *= inv; a3.y *= inv; a3.z *= inv; a3.w *= inv;
    q[0] = a0; q[1] = a1; q[2] = a2; q[3] = a3;
}

// ---------------------------------------------------------------------------
// K2/K4: dynamic routing. One wave (64 lanes) per node.
// lane = m*4 + g : m = neighbor index [0,16), g = d-quarter [0,4)
// Each lane holds z[m][k][g*4 .. g*4+3] for all k  -> 8 float4 registers.
// ---------------------------------------------------------------------------
__global__ __launch_bounds__(256)
void routing_kernel(const float* __restrict__ xn,
                    const int* __restrict__ nb,
                    float* __restrict__ out) {
    const int wave = threadIdx.x >> 6;
    const int lane = threadIdx.x & 63;
    const int node = blockIdx.x * 4 + wave;
    if (node >= N_NODES) return;
    const int m = lane >> 2;
    const int g = lane & 3;

    // gather neighbor row slice (once; reused across all 6 iterations)
    int idx = nb[node * M_NB + m];
    bool valid = (idx >= 0 && idx < N_NODES);   // index N == zero pad row
    const float* zrow = xn + (size_t)(valid ? idx : 0) * D_DIM;

    float4 z[K_CAPS];
#pragma unroll
    for (int k = 0; k < K_CAPS; ++k) {
        float4 v = *reinterpret_cast<const float4*>(zrow + k * DD + g * 4);
        if (!valid) { v.x = 0.f; v.y = 0.f; v.z = 0.f; v.w = 0.f; }
        z[k] = v;
    }

    // own normalized row (residual term), same slice layout
    const float* xrow = xn + (size_t)node * D_DIM;
    float4 xnr[K_CAPS];
#pragma unroll
    for (int k = 0; k < K_CAPS; ++k)
        xnr[k] = *reinterpret_cast<const float4*>(xrow + k * DD + g * 4);

    float4 u[K_CAPS];
#pragma unroll
    for (int k = 0; k < K_CAPS; ++k) u[k] = xnr[k];

    for (int it = 0; it < ROUTIT; ++it) {
        // ---- einsum1: logits p[m][k] = sum_d z[m,k,d] * u[k,d]
        float p[K_CAPS];
#pragma unroll
        for (int k = 0; k < K_CAPS; ++k) {
            float s = z[k].x * u[k].x + z[k].y * u[k].y
                    + z[k].z * u[k].z + z[k].w * u[k].w;
            s += __shfl_xor(s, 1);   // reduce over g (d quarters)
            s += __shfl_xor(s, 2);
            p[k] = s;
        }
        // ---- softmax over k (lane-local: this lane has all 8 k for its m)
        float mx = p[0];
#pragma unroll
        for (int k = 1; k < K_CAPS; ++k) mx = fmaxf(mx, p[k]);
        float sum = 0.f;
#pragma unroll
        for (int k = 0; k < K_CAPS; ++k) { p[k] = expf(p[k] - mx); sum += p[k]; }
        float pinv = 1.0f / sum;
#pragma unroll
        for (int k = 0; k < K_CAPS; ++k) p[k] *= pinv;

        // ---- einsum2: u[k,d] = sum_m z[m,k,d] * p[m,k]  (+ xn)
#pragma unroll
        for (int k = 0; k < K_CAPS; ++k) {
            u[k].x = z[k].x * p[k];
            u[k].y = z[k].y * p[k];
            u[k].z = z[k].z * p[k];
            u[k].w = z[k].w * p[k];
        }
#pragma unroll
        for (int mask = 4; mask <= 32; mask <<= 1) {
#pragma unroll
            for (int k = 0; k < K_CAPS; ++k) {
                u[k].x += __shfl_xor(u[k].x, mask);
                u[k].y += __shfl_xor(u[k].y, mask);
                u[k].z += __shfl_xor(u[k].z, mask);
                u[k].w += __shfl_xor(u[k].w, mask);
            }
        }
#pragma unroll
        for (int k = 0; k < K_CAPS; ++k) {
            u[k].x += xnr[k].x; u[k].y += xnr[k].y;
            u[k].z += xnr[k].z; u[k].w += xnr[k].w;
        }
        // ---- renormalize (all but last iteration)
        if (it < ROUTIT - 1) {
#pragma unroll
            for (int k = 0; k < K_CAPS; ++k) {
                float s = u[k].x * u[k].x + u[k].y * u[k].y
                        + u[k].z * u[k].z + u[k].w * u[k].w;
                s += __shfl_xor(s, 1);
                s += __shfl_xor(s, 2);
                float inv = 1.0f / fmaxf(sqrtf(s), 1e-12f);
                u[k].x *= inv; u[k].y *= inv; u[k].z *= inv; u[k].w *= inv;
            }
        }
    }

    // ---- output: relu(u). lanes 0..31 each store one float4 at offset lane*4
    // (lane = m*4+g, k=m<8 slice element index = m*16+g*4 = lane*4 -> coalesced)
    if (m < K_CAPS) {
        float4 v = u[m];
        v.x = fmaxf(v.x, 0.f); v.y = fmaxf(v.y, 0.f);
        v.z = fmaxf(v.z, 0.f); v.w = fmaxf(v.w, 0.f);
        *reinterpret_cast<float4*>(out + (size_t)node * D_DIM + lane * 4) = v;
    }
}

// ---------------------------------------------------------------------------
// K3: xn1 = normalize_per_capsule( relu( h0 @ W^T + b ) )
// W (=[col][k], row-major [D,D]) staged transposed in LDS: Wt[k*129+col]
// 256 threads: 2 rows per pass, thread = (r=tid>>7, col=tid&127)
// ---------------------------------------------------------------------------
__global__ __launch_bounds__(256)
void fc_norm_kernel(const float* __restrict__ h,
                    const float* __restrict__ W,
                    const float* __restrict__ b,
                    float* __restrict__ xn) {
    __shared__ float Wt[128 * 129];
    __shared__ float hrow[2][128];

    for (int i = threadIdx.x; i < 128 * 128; i += 256) {
        int col = i >> 7, k = i & 127;
        Wt[k * 129 + col] = W[i];          // write stride 129 -> conflict-free
    }
    __syncthreads();

    const int col = threadIdx.x & 127;
    const int r = threadIdx.x >> 7;
    const float bias = b[col];

    for (int row0 = blockIdx.x * 2; row0 < N_NODES; row0 += gridDim.x * 2) {
        int row = row0 + r;                 // N even -> both rows valid
        __syncthreads();
        hrow[r][col] = h[(size_t)row * D_DIM + col];
        __syncthreads();

        float acc = bias;
#pragma unroll 8
        for (int k = 0; k < 128; ++k)
            acc = fmaf(hrow[r][k], Wt[k * 129 + col], acc);
        acc = fmaxf(acc, 0.f);              // relu BEFORE normalize

        // per-capsule (16 consecutive cols, within one wave) norm reduce
        float s = acc * acc;
        s += __shfl_xor(s, 1);
        s += __shfl_xor(s, 2);
        s += __shfl_xor(s, 4);
        s += __shfl_xor(s, 8);
        float inv = 1.0f / fmaxf(sqrtf(s), 1e-12f);
        xn[(size_t)row * D_DIM + col] = acc * inv;
    }
}

// ---------------------------------------------------------------------------
extern "C" void kernel_launch(void* const* d_in, const int* in_sizes, int n_in,
                              void* d_out, int out_size, void* d_ws, size_t ws_size,
                              hipStream_t stream) {
    const float* x  = (const float*)d_in[0];
    const int*   nb = (const int*)d_in[1];
    const float* W  = (const float*)d_in[2];
    const float* bb = (const float*)d_in[3];
    float* out = (float*)d_out;

    float* xnbuf = (float*)d_ws;                          // 25.6 MB
    float* h0    = xnbuf + (size_t)N_NODES * D_DIM;       // 25.6 MB

    // layer 0
    normalize_kernel<<<(N_NODES * K_CAPS + 255) / 256, 256, 0, stream>>>(x, xnbuf);
    routing_kernel<<<(N_NODES + 3) / 4, 256, 0, stream>>>(xnbuf, nb, h0);
    // layer 1
    fc_norm_kernel<<<2048, 256, 0, stream>>>(h0, W, bb, xnbuf);
    routing_kernel<<<(N_NODES + 3) / 4, 256, 0, stream>>>(xnbuf, nb, out);
}

// Round 3
// 575.766 us; speedup vs baseline: 1.9091x; 1.9091x over previous
//
#include <hip/hip_runtime.h>
#include <math.h>

#define N_NODES 50000
#define M_NB 16
#define K_CAPS 8
#define DD 16
#define D_DIM 128
#define ROUTIT 6

// ---------------------------------------------------------------------------
// Cross-lane butterfly-add helpers (VALU, no DS pipe where possible)
// ---------------------------------------------------------------------------
template <int CTRL>
__device__ __forceinline__ float dpp_add(float x) {
    // x + x[lane ^ mask] via DPP fused add (quad_perm / mirror controls)
    int t = __builtin_amdgcn_update_dpp(0, __float_as_int(x), CTRL, 0xF, 0xF, true);
    return x + __int_as_float(t);
}

__device__ __forceinline__ float xor16_add(float x) {
#if __has_builtin(__builtin_amdgcn_permlane16_swap)
    unsigned xi = __float_as_uint(x);
    auto r = __builtin_amdgcn_permlane16_swap(xi, xi, false, false);
    // r[0],r[1] jointly hold {x[lane], x[lane^16]} at every lane -> sum = butterfly
    return __uint_as_float(r[0]) + __uint_as_float(r[1]);
#else
    return x + __int_as_float(__builtin_amdgcn_ds_swizzle(__float_as_int(x), 0x401F));
#endif
}

__device__ __forceinline__ float xor32_add(float x) {
#if __has_builtin(__builtin_amdgcn_permlane32_swap)
    unsigned xi = __float_as_uint(x);
    auto r = __builtin_amdgcn_permlane32_swap(xi, xi, false, false);
    return __uint_as_float(r[0]) + __uint_as_float(r[1]);
#else
    return x + __shfl_xor(x, 32);
#endif
}

__device__ __forceinline__ float fast_rcp(float x) {
#if __has_builtin(__builtin_amdgcn_rcpf)
    return __builtin_amdgcn_rcpf(x);
#else
    return 1.0f / x;
#endif
}

__device__ __forceinline__ float fast_rsq(float x) {
#if __has_builtin(__builtin_amdgcn_rsqf)
    return __builtin_amdgcn_rsqf(x);
#else
    return 1.0f / sqrtf(x);
#endif
}

// ---------------------------------------------------------------------------
// K1: per-capsule L2 normalize
// ---------------------------------------------------------------------------
__global__ void normalize_kernel(const float* __restrict__ x,
                                 float* __restrict__ xn) {
    int tid = blockIdx.x * blockDim.x + threadIdx.x;
    if (tid >= N_NODES * K_CAPS) return;
    const float4* p = reinterpret_cast<const float4*>(x + (size_t)tid * DD);
    float4 a0 = p[0], a1 = p[1], a2 = p[2], a3 = p[3];
    float s = a0.x*a0.x + a0.y*a0.y + a0.z*a0.z + a0.w*a0.w
            + a1.x*a1.x + a1.y*a1.y + a1.z*a1.z + a1.w*a1.w
            + a2.x*a2.x + a2.y*a2.y + a2.z*a2.z + a2.w*a2.w
            + a3.x*a3.x + a3.y*a3.y + a3.z*a3.z + a3.w*a3.w;
    float inv = 1.0f / fmaxf(sqrtf(s), 1e-12f);
    float4* q = reinterpret_cast<float4*>(xn + (size_t)tid * DD);
    a0.x *= inv; a0.y *= inv; a0.z *= inv; a0.w *= inv;
    a1.x *= inv; a1.y *= inv; a1.z *= inv; a1.w *= inv;
    a2.x *= inv; a2.y *= inv; a2.z *= inv; a2.w *= inv;
    a3.x *= inv; a3.y *= inv; a3.z *= inv; a3.w *= inv;
    q[0] = a0; q[1] = a1; q[2] = a2; q[3] = a3;
}

// ---------------------------------------------------------------------------
// K2/K4: dynamic routing. One wave per node.
// lane = m + 16*g : m = neighbor [0,16) in lane bits[3:0], g = d-quarter bits[5:4]
// m-reduction (einsum2): lane-xor masks {1,2,7,15} -> all DPP (pure VALU)
// g-reduction (einsum1 dot, norm): xor16 + xor32 via permlane swaps
// ---------------------------------------------------------------------------
__global__ __launch_bounds__(256, 4)
void routing_kernel(const float* __restrict__ xn,
                    const int* __restrict__ nb,
                    float* __restrict__ out) {
    const int wave = threadIdx.x >> 6;
    const int lane = threadIdx.x & 63;
    const int node = blockIdx.x * 4 + wave;
    if (node >= N_NODES) return;
    const int m = lane & 15;
    const int g = lane >> 4;

    // gather neighbor slice once; reused across all 6 iterations
    int idx = nb[node * M_NB + m];
    bool valid = ((unsigned)idx < (unsigned)N_NODES);   // index N == zero pad row
    const float* zrow = xn + (size_t)(valid ? idx : 0) * D_DIM + g * 4;

    float4 z[K_CAPS];
#pragma unroll
    for (int k = 0; k < K_CAPS; ++k) {
        float4 v = *reinterpret_cast<const float4*>(zrow + k * DD);
        if (!valid) { v.x = 0.f; v.y = 0.f; v.z = 0.f; v.w = 0.f; }
        z[k] = v;
    }

    // own normalized row: u init (unscaled) + xs = xn/16 (residual folded per-partial)
    const float* xrow = xn + (size_t)node * D_DIM + g * 4;
    float4 u[K_CAPS], xs[K_CAPS];
#pragma unroll
    for (int k = 0; k < K_CAPS; ++k) {
        float4 v = *reinterpret_cast<const float4*>(xrow + k * DD);
        u[k] = v;
        xs[k].x = v.x * 0.0625f; xs[k].y = v.y * 0.0625f;
        xs[k].z = v.z * 0.0625f; xs[k].w = v.w * 0.0625f;
    }

    for (int it = 0; it < ROUTIT; ++it) {
        // ---- einsum1: logits p[m][k] = sum_d z[m,k,d]*u[k,d]; reduce over g
        float p[K_CAPS];
#pragma unroll
        for (int k = 0; k < K_CAPS; ++k) {
            float s = z[k].x * u[k].x;
            s = fmaf(z[k].y, u[k].y, s);
            s = fmaf(z[k].z, u[k].z, s);
            s = fmaf(z[k].w, u[k].w, s);
            p[k] = s;
        }
#pragma unroll
        for (int k = 0; k < K_CAPS; ++k) p[k] = xor16_add(p[k]);
#pragma unroll
        for (int k = 0; k < K_CAPS; ++k) p[k] = xor32_add(p[k]);

        // ---- softmax over k (lane-local). |logit| <= 1 (unit vectors) -> no max
        float sum = 0.f;
#pragma unroll
        for (int k = 0; k < K_CAPS; ++k) { p[k] = __expf(p[k]); sum += p[k]; }
        float pinv = fast_rcp(sum);
#pragma unroll
        for (int k = 0; k < K_CAPS; ++k) p[k] *= pinv;

        // ---- einsum2 partials with folded residual: z*p + xn/16
#pragma unroll
        for (int k = 0; k < K_CAPS; ++k) {
            u[k].x = fmaf(z[k].x, p[k], xs[k].x);
            u[k].y = fmaf(z[k].y, p[k], xs[k].y);
            u[k].z = fmaf(z[k].z, p[k], xs[k].z);
            u[k].w = fmaf(z[k].w, p[k], xs[k].w);
        }
        // ---- butterfly over m (lane bits[3:0]) with DPP-only masks {1,2,7,15}
#define DPP_STAGE(CTRL)                                          \
        _Pragma("unroll")                                        \
        for (int k = 0; k < K_CAPS; ++k) {                       \
            u[k].x = dpp_add<CTRL>(u[k].x);                      \
            u[k].y = dpp_add<CTRL>(u[k].y);                      \
            u[k].z = dpp_add<CTRL>(u[k].z);                      \
            u[k].w = dpp_add<CTRL>(u[k].w);                      \
        }
        DPP_STAGE(0xB1)    // quad_perm [1,0,3,2]  : xor 1
        DPP_STAGE(0x4E)    // quad_perm [2,3,0,1]  : xor 2
        DPP_STAGE(0x141)   // row_half_mirror      : xor 7
        DPP_STAGE(0x140)   // row_mirror           : xor 15
#undef DPP_STAGE

        // ---- renormalize (all but last iteration)
        if (it < ROUTIT - 1) {
            float s[K_CAPS];
#pragma unroll
            for (int k = 0; k < K_CAPS; ++k) {
                float t = u[k].x * u[k].x;
                t = fmaf(u[k].y, u[k].y, t);
                t = fmaf(u[k].z, u[k].z, t);
                t = fmaf(u[k].w, u[k].w, t);
                s[k] = t;
            }
#pragma unroll
            for (int k = 0; k < K_CAPS; ++k) s[k] = xor16_add(s[k]);
#pragma unroll
            for (int k = 0; k < K_CAPS; ++k) {
                float t = xor32_add(s[k]);
                float inv = fast_rsq(fmaxf(t, 1e-24f));
                u[k].x *= inv; u[k].y *= inv; u[k].z *= inv; u[k].w *= inv;
            }
        }
    }

    // ---- output: relu(u). lane (k'=m<8, g) stores u[k'] slice -> 512B/wave contiguous
    if (m < K_CAPS) {
        float4 v = u[m];
        v.x = fmaxf(v.x, 0.f); v.y = fmaxf(v.y, 0.f);
        v.z = fmaxf(v.z, 0.f); v.w = fmaxf(v.w, 0.f);
        *reinterpret_cast<float4*>(out + (size_t)node * D_DIM + m * DD + g * 4) = v;
    }
}

// ---------------------------------------------------------------------------
// K3: xn1 = normalize_per_capsule( relu( h0 @ W^T + b ) )
// ---------------------------------------------------------------------------
__global__ __launch_bounds__(256)
void fc_norm_kernel(const float* __restrict__ h,
                    const float* __restrict__ W,
                    const float* __restrict__ b,
                    float* __restrict__ xn) {
    __shared__ float Wt[128 * 129];
    __shared__ float hrow[2][128];

    for (int i = threadIdx.x; i < 128 * 128; i += 256) {
        int col = i >> 7, k = i & 127;
        Wt[k * 129 + col] = W[i];          // write stride 129 -> conflict-free
    }
    __syncthreads();

    const int col = threadIdx.x & 127;
    const int r = threadIdx.x >> 7;
    const float bias = b[col];

    for (int row0 = blockIdx.x * 2; row0 < N_NODES; row0 += gridDim.x * 2) {
        int row = row0 + r;                 // N even -> both rows valid
        __syncthreads();
        hrow[r][col] = h[(size_t)row * D_DIM + col];
        __syncthreads();

        float acc = bias;
#pragma unroll 8
        for (int k = 0; k < 128; ++k)
            acc = fmaf(hrow[r][k], Wt[k * 129 + col], acc);
        acc = fmaxf(acc, 0.f);              // relu BEFORE normalize

        // per-capsule (16 consecutive cols, within one wave) norm reduce
        float s = acc * acc;
        s += __shfl_xor(s, 1);
        s += __shfl_xor(s, 2);
        s += __shfl_xor(s, 4);
        s += __shfl_xor(s, 8);
        float inv = 1.0f / fmaxf(sqrtf(s), 1e-12f);
        xn[(size_t)row * D_DIM + col] = acc * inv;
    }
}

// ---------------------------------------------------------------------------
extern "C" void kernel_launch(void* const* d_in, const int* in_sizes, int n_in,
                              void* d_out, int out_size, void* d_ws, size_t ws_size,
                              hipStream_t stream) {
    const float* x  = (const float*)d_in[0];
    const int*   nb = (const int*)d_in[1];
    const float* W  = (const float*)d_in[2];
    const float* bb = (const float*)d_in[3];
    float* out = (float*)d_out;

    float* xnbuf = (float*)d_ws;                          // 25.6 MB
    float* h0    = xnbuf + (size_t)N_NODES * D_DIM;       // 25.6 MB

    // layer 0
    normalize_kernel<<<(N_NODES * K_CAPS + 255) / 256, 256, 0, stream>>>(x, xnbuf);
    routing_kernel<<<(N_NODES + 3) / 4, 256, 0, stream>>>(xnbuf, nb, h0);
    // layer 1
    fc_norm_kernel<<<2048, 256, 0, stream>>>(h0, W, bb, xnbuf);
    routing_kernel<<<(N_NODES + 3) / 4, 256, 0, stream>>>(xnbuf, nb, out);
}